// Round 12
// baseline (163.479 us; speedup 1.0000x reference)
//
#include <hip/hip_runtime.h>
#include <math.h>

typedef unsigned short u16;
typedef unsigned int   u32;

#define B_       64
#define NN_      64
#define HL_      50
#define IN_DIM   384
#define POS_DIM  64
#define ATT_DIM  256
#define NEWS_DIM 448   // IN_DIM + POS_DIM

typedef __attribute__((ext_vector_type(8))) short short8;   // bf16x8 MFMA frag
typedef __attribute__((ext_vector_type(4))) float f32x4;    // MFMA acc

#if __has_builtin(__builtin_amdgcn_exp2f)
#define EXP2F(x) __builtin_amdgcn_exp2f(x)
#else
#define EXP2F(x) exp2f(x)
#endif
#if __has_builtin(__builtin_amdgcn_rcpf)
#define RCPF(x) __builtin_amdgcn_rcpf(x)
#else
#define RCPF(x) (1.0f/(x))
#endif

__device__ __forceinline__ u16 f2bf(float f) {
    union { float f; u32 i; } v; v.f = f;
    u32 r = v.i + 0x7fffu + ((v.i >> 16) & 1u);   // RNE
    return (u16)(r >> 16);
}
__device__ __forceinline__ float bf2f(u16 u) {
    union { u32 i; float f; } v; v.i = ((u32)u) << 16; return v.f;
}
__device__ __forceinline__ uint2 pack4(float4 v) {
    return make_uint2((u32)f2bf(v.x) | ((u32)f2bf(v.y) << 16),
                      (u32)f2bf(v.z) | ((u32)f2bf(v.w) << 16));
}
// tanh(x) = 1 - 2/(1+2^(x*2*log2e)); v_exp+v_rcp saturate correctly at +-inf.
__device__ __forceinline__ float fast_tanh(float x) {
    float e = EXP2F(x * 2.88539008f);
    return 1.0f - 2.0f * RCPF(1.0f + e);
}

// prep segments, in 4-f32 chunks
#define C_W   57344u     // W1 (256x896) -> Wbf
#define C_NV  393216u    // newsv (4096x384) -> nv_bf AND nf f32 head
#define C_LG  307200u    // logv (3200x384) -> lf_bf head
#define C_PS  51200u     // pos rows 1..50 -> lf_bf tail
#define C_NZ  65536u     // nf f32 zero tail (4096x64)
#define C_TOT (C_W + C_NV + C_LG + C_PS + C_NZ)   // 874,496 = 3416*256

// ---------------- K0: bf16-convert W1/newsv/lf into ws; nf (f32) -> d_out.
__global__ __launch_bounds__(256) void prep_k(
    const float* __restrict__ W1, const float* __restrict__ newsv,
    const float* __restrict__ logv, const float* __restrict__ pos,
    u16* __restrict__ Wbf, u16* __restrict__ nv_bf, u16* __restrict__ lf_bf,
    float* __restrict__ nf)
{
    u32 i = blockIdx.x * 256u + threadIdx.x;
    if (i < C_W) {                                   // W1 -> Wbf
        float4 v = *(const float4*)(W1 + (size_t)i * 4u);
        *(uint2*)(Wbf + (size_t)i * 4u) = pack4(v);
        return;
    }
    i -= C_W;
    if (i < C_NV) {                                  // newsv -> nv_bf + nf head
        float4 v = *(const float4*)(newsv + (size_t)i * 4u);
        *(uint2*)(nv_bf + (size_t)i * 4u) = pack4(v);
        u32 e = i * 4u, r = e / IN_DIM, d = e - r * IN_DIM;
        *(float4*)(nf + (size_t)r * NEWS_DIM + d) = v;
        return;
    }
    i -= C_NV;
    if (i < C_LG) {                                  // logv -> lf_bf head
        float4 v = *(const float4*)(logv + (size_t)i * 4u);
        u32 e = i * 4u, r = e / IN_DIM, d = e - r * IN_DIM;
        *(uint2*)(lf_bf + (size_t)r * NEWS_DIM + d) = pack4(v);
        return;
    }
    i -= C_LG;
    if (i < C_PS) {                                  // pos rows 1..50 -> lf_bf tail
        u32 e = i * 4u, r = e / POS_DIM, d = e - r * POS_DIM;
        u32 h = r % HL_;
        float4 v = *(const float4*)(pos + (size_t)(1u + h) * POS_DIM + d);
        *(uint2*)(lf_bf + (size_t)r * NEWS_DIM + IN_DIM + d) = pack4(v);
        return;
    }
    i -= C_PS;
    if (i < C_NZ) {                                  // nf zero tail
        u32 e = i * 4u, r = e / POS_DIM, d = e - r * POS_DIM;
        *(float4*)(nf + (size_t)r * NEWS_DIM + IN_DIM + d) = make_float4(0.f, 0.f, 0.f, 0.f);
    }
}

// ---------------- K1: fused NT GEMMs, pure bf16 16B loads (R9/R11-proven form).
// bid < 256: pn[4096x256] = nv_bf . Wbf[:, :384]^T + b1
// bid >= 256: plT[(b*256+a)*50+h] = lf_bf . Wbf[:, 448:]^T  (transposed store)
__global__ __launch_bounds__(64) void gemm_k(
    const u16* __restrict__ nv_bf, const u16* __restrict__ lf_bf,
    const u16* __restrict__ Wbf, const float* __restrict__ b1,
    float* __restrict__ pn, float* __restrict__ plT)
{
    int bid = blockIdx.x;
    int lane = threadIdx.x;
    int m = lane & 15, q = lane >> 4;
    bool is_pn = bid < 256;
    int r0, c0, lda, koff, klen;
    const u16* A;
    if (is_pn) { r0 = (bid & 63) * 64;       c0 = (bid >> 6) * 64; A = nv_bf; lda = IN_DIM;   koff = 0;        klen = IN_DIM; }
    else { int b2 = bid - 256; r0 = (b2 % 50) * 64; c0 = (b2 / 50) * 64; A = lf_bf; lda = NEWS_DIM; koff = NEWS_DIM; klen = NEWS_DIM; }

    f32x4 acc[4][4];
#pragma unroll
    for (int a = 0; a < 4; a++)
#pragma unroll
        for (int b = 0; b < 4; b++) acc[a][b] = (f32x4){0.f, 0.f, 0.f, 0.f};

    const u16* Ap = A + (size_t)(r0 + m) * lda + q * 8;
    const u16* Wp = Wbf + (size_t)(c0 + m) * (2 * NEWS_DIM) + koff + q * 8;

    for (int k = 0; k < klen; k += 32) {
        short8 af[4], wf[4];
#pragma unroll
        for (int rt = 0; rt < 4; rt++) af[rt] = *(const short8*)(Ap + rt * 16 * lda + k);
#pragma unroll
        for (int ct = 0; ct < 4; ct++) wf[ct] = *(const short8*)(Wp + ct * 16 * (2 * NEWS_DIM) + k);
#pragma unroll
        for (int rt = 0; rt < 4; rt++)
#pragma unroll
            for (int ct = 0; ct < 4; ct++)
                acc[rt][ct] = __builtin_amdgcn_mfma_f32_16x16x32_bf16(
                    af[rt], wf[ct], acc[rt][ct], 0, 0, 0);
    }
    // C/D layout: col = lane&15, row = (lane>>4)*4 + i  [m89]
#pragma unroll
    for (int rt = 0; rt < 4; rt++)
#pragma unroll
        for (int ct = 0; ct < 4; ct++)
#pragma unroll
            for (int i = 0; i < 4; i++) {
                int gr = r0 + rt * 16 + q * 4 + i;
                int gc = c0 + ct * 16 + m;
                float v = acc[rt][ct][i];
                if (is_pn) {
                    pn[(size_t)gr * ATT_DIM + gc] = v + b1[gc];
                } else {
                    int bb = gr / HL_, hh = gr - bb * HL_;
                    plT[(size_t)(bb * ATT_DIM + gc) * HL_ + hh] = v;
                }
            }
}

// ---------------- K2: FUSED logits -> masked softmax -> out = attn x lf.
// TWO WAVES PER (b,n), split by ATT_DIM half -> 8192 waves = 8/SIMD (HW max).
// R11 at 4/SIMD was still latency-exposed on the 256 serial pl loads; grid was
// capped at one wave per (b,n), so the work splits instead. Partial logits
// combine via 1KB LDS + 2 barriers; softmax duplicated in both waves (cheap);
// phase 2 d-chunks split 4/3. No duplicated pn/pl/lf traffic.
__global__ __launch_bounds__(256) void attn_out_k(
    const float* __restrict__ pn, const float* __restrict__ plT,
    const float* __restrict__ w2, const int* __restrict__ lmask,
    const u16* __restrict__ lf_bf, float* __restrict__ out)
{
    __shared__ float part_s[4][64];            // partial logits, then attn
    int lane = threadIdx.x & 63;
    int wid = (int)(threadIdx.x >> 6);
    int half = wid & 1;                        // a-half
    int g = blockIdx.x * 2 + (wid >> 1);       // (b,n) id in [0,4096)
    int b = g >> 6;
    int hl = (lane < HL_) ? lane : (HL_ - 1);  // clamp reads
    int mv = (lane < HL_) ? lmask[b * HL_ + lane] : 0;   // prefetch early
    const float* pr = pn + (size_t)g * ATT_DIM + half * 128;
    const float* pl = plT + ((size_t)b * ATT_DIM + half * 128) * HL_ + hl;
    const float* w2h = w2 + half * 128;

    float a0 = 0.f, a1 = 0.f, a2 = 0.f, a3 = 0.f;
#pragma unroll 4
    for (int a = 0; a < 128; a += 4) {
        float4 w4 = *(const float4*)(w2h + a);
        float4 p  = *(const float4*)(pr + a);  // wave-uniform
        float l0 = pl[(a + 0) * HL_];
        float l1 = pl[(a + 1) * HL_];
        float l2 = pl[(a + 2) * HL_];
        float l3 = pl[(a + 3) * HL_];
        a0 = __builtin_fmaf(fast_tanh(p.x + l0), w4.x, a0);
        a1 = __builtin_fmaf(fast_tanh(p.y + l1), w4.y, a1);
        a2 = __builtin_fmaf(fast_tanh(p.z + l2), w4.z, a2);
        a3 = __builtin_fmaf(fast_tanh(p.w + l3), w4.w, a3);
    }
    part_s[wid][lane] = (a0 + a1) + (a2 + a3);
    __syncthreads();
    float acc = part_s[wid][lane] + part_s[wid ^ 1][lane];
    __syncthreads();                           // partner done reading partials

    float logit = mv ? acc : -1e9f;            // b2 dropped: softmax-invariant
    float mx = logit;
#pragma unroll
    for (int o = 32; o > 0; o >>= 1) mx = fmaxf(mx, __shfl_xor(mx, o));
    float e = EXP2F((logit - mx) * 1.44269504f);   // masked lanes -> 0
    float s = e;
#pragma unroll
    for (int o = 32; o > 0; o >>= 1) s += __shfl_xor(s, o);
    part_s[wid][lane] = e * RCPF(s);
    // no barrier: same wave writes & reads its own slice (lgkmcnt enforced)

    // phase 2: out[b,n][d]; wave covers d = half*256 + lane + 64j
    // (half 0: j<4 -> d<256; half 1: j<3 -> d in [256,448)). lf rows 128B coalesced.
    const u16* lfb = lf_bf + (size_t)b * HL_ * NEWS_DIM + half * 256 + lane;
    int nj = half ? 3 : 4;
    float acc7[4];
#pragma unroll
    for (int j = 0; j < 4; j++) acc7[j] = 0.f;
    for (int h = 0; h < HL_; h++) {
        float av = part_s[wid][h];             // LDS broadcast
        const u16* row = lfb + (size_t)h * NEWS_DIM;
#pragma unroll
        for (int j = 0; j < 4; j++)
            if (j < nj) acc7[j] = fmaf(av, bf2f(row[64 * j]), acc7[j]);
    }
    float* o0 = out + (size_t)g * NEWS_DIM + half * 256 + lane;
#pragma unroll
    for (int j = 0; j < 4; j++)
        if (j < nj) o0[64 * j] = acc7[j];
}

extern "C" void kernel_launch(void* const* d_in, const int* in_sizes, int n_in,
                              void* d_out, int out_size, void* d_ws, size_t ws_size,
                              hipStream_t stream) {
    const float* logv  = (const float*)d_in[0];  // (64,50,384) f32
    const int*   lmask = (const int*)d_in[1];    // (64,50) i32
    const float* newsv = (const float*)d_in[2];  // (64,64,384) f32
    const float* pos   = (const float*)d_in[3];  // (100,64) f32; row 0 == 0
    const float* W1    = (const float*)d_in[4];  // (256,896) f32
    const float* b1    = (const float*)d_in[5];  // (256,) f32
    const float* w2    = (const float*)d_in[6];  // (1,256) f32
    // b2 unused (softmax-invariant shift)

    float* out = (float*)d_out;                  // [user_log | nf], f32
    float* nf  = out + (size_t)B_ * NN_ * NEWS_DIM;

    // d_ws ~256 MiB. Byte offsets, 16B aligned:
    char* ws = (char*)d_ws;
    u16*   lf_bf = (u16*)(ws + 0);               // 3200x448 bf16  (2,867,200 B)
    u16*   Wbf   = (u16*)(ws + 2867200);         // 256x896 bf16   (458,752 B)
    u16*   nv_bf = (u16*)(ws + 3325952);         // 4096x384 bf16  (3,145,728 B)
    float* pn    = (float*)(ws + 6471680);       // 4096x256 f32   (4,194,304 B)
    float* plT   = (float*)(ws + 10665984);      // 64x256x50 f32  (3,276,800 B)

    prep_k    <<<C_TOT / 256, 256, 0, stream>>>(W1, newsv, logv, pos,
                                                Wbf, nv_bf, lf_bf, nf);
    gemm_k    <<<456, 64, 0, stream>>>(nv_bf, lf_bf, Wbf, b1, pn, plT);
    attn_out_k<<<2048, 256, 0, stream>>>(pn, plT, w2, lmask, lf_bf, out);
}

// Round 13
// 133.253 us; speedup vs baseline: 1.2268x; 1.2268x over previous
//
#include <hip/hip_runtime.h>
#include <math.h>

typedef unsigned short u16;
typedef unsigned int   u32;

#define B_       64
#define NN_      64
#define HL_      50
#define IN_DIM   384
#define POS_DIM  64
#define ATT_DIM  256
#define NEWS_DIM 448   // IN_DIM + POS_DIM

typedef __attribute__((ext_vector_type(8))) short short8;   // bf16x8 MFMA frag
typedef __attribute__((ext_vector_type(4))) float f32x4;    // MFMA acc

#if __has_builtin(__builtin_amdgcn_exp2f)
#define EXP2F(x) __builtin_amdgcn_exp2f(x)
#else
#define EXP2F(x) exp2f(x)
#endif
#if __has_builtin(__builtin_amdgcn_rcpf)
#define RCPF(x) __builtin_amdgcn_rcpf(x)
#else
#define RCPF(x) (1.0f/(x))
#endif

__device__ __forceinline__ u16 f2bf(float f) {
    union { float f; u32 i; } v; v.f = f;
    u32 r = v.i + 0x7fffu + ((v.i >> 16) & 1u);   // RNE
    return (u16)(r >> 16);
}
__device__ __forceinline__ float bf2f(u16 u) {
    union { u32 i; float f; } v; v.i = ((u32)u) << 16; return v.f;
}
__device__ __forceinline__ uint2 pack4(float4 v) {
    return make_uint2((u32)f2bf(v.x) | ((u32)f2bf(v.y) << 16),
                      (u32)f2bf(v.z) | ((u32)f2bf(v.w) << 16));
}
// tanh(x) = 1 - 2/(1+2^(x*2*log2e)); v_exp+v_rcp saturate correctly at +-inf.
__device__ __forceinline__ float fast_tanh(float x) {
    float e = EXP2F(x * 2.88539008f);
    return 1.0f - 2.0f * RCPF(1.0f + e);
}

// prep segments, in 4-f32 chunks
#define C_W   57344u     // W1 (256x896) -> Wbf
#define C_NV  393216u    // newsv (4096x384) -> nv_bf AND nf f32 head
#define C_LG  307200u    // logv (3200x384) -> lf_bf head
#define C_PS  51200u     // pos rows 1..50 -> lf_bf tail
#define C_NZ  65536u     // nf f32 zero tail (4096x64)
#define C_TOT (C_W + C_NV + C_LG + C_PS + C_NZ)   // 874,496 = 3416*256

// ---------------- K0: bf16-convert W1/newsv/lf into ws; nf (f32) -> d_out.
__global__ __launch_bounds__(256) void prep_k(
    const float* __restrict__ W1, const float* __restrict__ newsv,
    const float* __restrict__ logv, const float* __restrict__ pos,
    u16* __restrict__ Wbf, u16* __restrict__ nv_bf, u16* __restrict__ lf_bf,
    float* __restrict__ nf)
{
    u32 i = blockIdx.x * 256u + threadIdx.x;
    if (i < C_W) {                                   // W1 -> Wbf
        float4 v = *(const float4*)(W1 + (size_t)i * 4u);
        *(uint2*)(Wbf + (size_t)i * 4u) = pack4(v);
        return;
    }
    i -= C_W;
    if (i < C_NV) {                                  // newsv -> nv_bf + nf head
        float4 v = *(const float4*)(newsv + (size_t)i * 4u);
        *(uint2*)(nv_bf + (size_t)i * 4u) = pack4(v);
        u32 e = i * 4u, r = e / IN_DIM, d = e - r * IN_DIM;
        *(float4*)(nf + (size_t)r * NEWS_DIM + d) = v;
        return;
    }
    i -= C_NV;
    if (i < C_LG) {                                  // logv -> lf_bf head
        float4 v = *(const float4*)(logv + (size_t)i * 4u);
        u32 e = i * 4u, r = e / IN_DIM, d = e - r * IN_DIM;
        *(uint2*)(lf_bf + (size_t)r * NEWS_DIM + d) = pack4(v);
        return;
    }
    i -= C_LG;
    if (i < C_PS) {                                  // pos rows 1..50 -> lf_bf tail
        u32 e = i * 4u, r = e / POS_DIM, d = e - r * POS_DIM;
        u32 h = r % HL_;
        float4 v = *(const float4*)(pos + (size_t)(1u + h) * POS_DIM + d);
        *(uint2*)(lf_bf + (size_t)r * NEWS_DIM + IN_DIM + d) = pack4(v);
        return;
    }
    i -= C_PS;
    if (i < C_NZ) {                                  // nf zero tail
        u32 e = i * 4u, r = e / POS_DIM, d = e - r * POS_DIM;
        *(float4*)(nf + (size_t)r * NEWS_DIM + IN_DIM + d) = make_float4(0.f, 0.f, 0.f, 0.f);
    }
}

// ---------------- K1: fused NT GEMMs, pure bf16 16B loads (R9/R11-proven form).
// bid < 256: pn[4096x256] = nv_bf . Wbf[:, :384]^T + b1
// bid >= 256: plT[(b*256+a)*50+h] = lf_bf . Wbf[:, 448:]^T  (transposed store)
__global__ __launch_bounds__(64) void gemm_k(
    const u16* __restrict__ nv_bf, const u16* __restrict__ lf_bf,
    const u16* __restrict__ Wbf, const float* __restrict__ b1,
    float* __restrict__ pn, float* __restrict__ plT)
{
    int bid = blockIdx.x;
    int lane = threadIdx.x;
    int m = lane & 15, q = lane >> 4;
    bool is_pn = bid < 256;
    int r0, c0, lda, koff, klen;
    const u16* A;
    if (is_pn) { r0 = (bid & 63) * 64;       c0 = (bid >> 6) * 64; A = nv_bf; lda = IN_DIM;   koff = 0;        klen = IN_DIM; }
    else { int b2 = bid - 256; r0 = (b2 % 50) * 64; c0 = (b2 / 50) * 64; A = lf_bf; lda = NEWS_DIM; koff = NEWS_DIM; klen = NEWS_DIM; }

    f32x4 acc[4][4];
#pragma unroll
    for (int a = 0; a < 4; a++)
#pragma unroll
        for (int b = 0; b < 4; b++) acc[a][b] = (f32x4){0.f, 0.f, 0.f, 0.f};

    const u16* Ap = A + (size_t)(r0 + m) * lda + q * 8;
    const u16* Wp = Wbf + (size_t)(c0 + m) * (2 * NEWS_DIM) + koff + q * 8;

    for (int k = 0; k < klen; k += 32) {
        short8 af[4], wf[4];
#pragma unroll
        for (int rt = 0; rt < 4; rt++) af[rt] = *(const short8*)(Ap + rt * 16 * lda + k);
#pragma unroll
        for (int ct = 0; ct < 4; ct++) wf[ct] = *(const short8*)(Wp + ct * 16 * (2 * NEWS_DIM) + k);
#pragma unroll
        for (int rt = 0; rt < 4; rt++)
#pragma unroll
            for (int ct = 0; ct < 4; ct++)
                acc[rt][ct] = __builtin_amdgcn_mfma_f32_16x16x32_bf16(
                    af[rt], wf[ct], acc[rt][ct], 0, 0, 0);
    }
    // C/D layout: col = lane&15, row = (lane>>4)*4 + i  [m89]
#pragma unroll
    for (int rt = 0; rt < 4; rt++)
#pragma unroll
        for (int ct = 0; ct < 4; ct++)
#pragma unroll
            for (int i = 0; i < 4; i++) {
                int gr = r0 + rt * 16 + q * 4 + i;
                int gc = c0 + ct * 16 + m;
                float v = acc[rt][ct][i];
                if (is_pn) {
                    pn[(size_t)gr * ATT_DIM + gc] = v + b1[gc];
                } else {
                    int bb = gr / HL_, hh = gr - bb * HL_;
                    plT[(size_t)(bb * ATT_DIM + gc) * HL_ + hh] = v;
                }
            }
}

// ---------------- K2: FUSED logits -> masked softmax -> out = attn x lf.
// ONE WAVE PER (b,n), 4096 waves = 4/SIMD. Empirically the optimum:
//   R10 (2 waves/SIMD, chunk-staged LDS, barriers): 48us, VALUBusy 34%
//   R11 (this form, direct pl loads, no barriers):  <44us -- best total 132.1
//   R12 (8 waves/SIMD, split-a, 2 barriers):        65us, VALUBusy 28%
// More TLP halves per-wave ILP and raises L2 queueing; less TLP exposes latency.
__global__ __launch_bounds__(256) void attn_out_k(
    const float* __restrict__ pn, const float* __restrict__ plT,
    const float* __restrict__ w2, const int* __restrict__ lmask,
    const u16* __restrict__ lf_bf, float* __restrict__ out)
{
    __shared__ float at_s[4][64];              // per-wave attn slices, 1 KB
    int lane = threadIdx.x & 63;
    int wid = (int)(threadIdx.x >> 6);
    int g = blockIdx.x * 4 + wid;              // wave id in [0,4096)
    int b = g >> 6;
    int hl = (lane < HL_) ? lane : (HL_ - 1);  // clamp reads
    const float* pr = pn + (size_t)g * ATT_DIM;
    const float* pl = plT + (size_t)b * ATT_DIM * HL_ + hl;

    float a0 = 0.f, a1 = 0.f, a2 = 0.f, a3 = 0.f;
#pragma unroll 4
    for (int a = 0; a < ATT_DIM; a += 4) {
        float4 w4 = *(const float4*)(w2 + a);
        float4 p  = *(const float4*)(pr + a);  // wave-uniform
        float l0 = pl[(a + 0) * HL_];
        float l1 = pl[(a + 1) * HL_];
        float l2 = pl[(a + 2) * HL_];
        float l3 = pl[(a + 3) * HL_];
        a0 = __builtin_fmaf(fast_tanh(p.x + l0), w4.x, a0);
        a1 = __builtin_fmaf(fast_tanh(p.y + l1), w4.y, a1);
        a2 = __builtin_fmaf(fast_tanh(p.z + l2), w4.z, a2);
        a3 = __builtin_fmaf(fast_tanh(p.w + l3), w4.w, a3);
    }
    float acc = (a0 + a1) + (a2 + a3);
    int mv = (lane < HL_) ? lmask[b * HL_ + lane] : 0;
    float logit = mv ? acc : -1e9f;            // b2 dropped: softmax-invariant
    float mx = logit;
#pragma unroll
    for (int o = 32; o > 0; o >>= 1) mx = fmaxf(mx, __shfl_xor(mx, o));
    float e = EXP2F((logit - mx) * 1.44269504f);   // masked lanes -> 0
    float s = e;
#pragma unroll
    for (int o = 32; o > 0; o >>= 1) s += __shfl_xor(s, o);
    at_s[wid][lane] = e * RCPF(s);
    // no barrier: same wave writes & reads its own slice (lgkmcnt enforced)

    // phase 2: out[b,n][d], d = lane + 64j (j<7); lf rows coalesced 128B (L2-hit).
    const u16* lfb = lf_bf + (size_t)b * HL_ * NEWS_DIM + lane;
    float acc7[7];
#pragma unroll
    for (int j = 0; j < 7; j++) acc7[j] = 0.f;
    for (int h = 0; h < HL_; h++) {
        float av = at_s[wid][h];               // LDS broadcast
        const u16* row = lfb + (size_t)h * NEWS_DIM;
#pragma unroll
        for (int j = 0; j < 7; j++)
            acc7[j] = fmaf(av, bf2f(row[64 * j]), acc7[j]);
    }
    float* o0 = out + (size_t)g * NEWS_DIM + lane;
#pragma unroll
    for (int j = 0; j < 7; j++) o0[64 * j] = acc7[j];
}

extern "C" void kernel_launch(void* const* d_in, const int* in_sizes, int n_in,
                              void* d_out, int out_size, void* d_ws, size_t ws_size,
                              hipStream_t stream) {
    const float* logv  = (const float*)d_in[0];  // (64,50,384) f32
    const int*   lmask = (const int*)d_in[1];    // (64,50) i32
    const float* newsv = (const float*)d_in[2];  // (64,64,384) f32
    const float* pos   = (const float*)d_in[3];  // (100,64) f32; row 0 == 0
    const float* W1    = (const float*)d_in[4];  // (256,896) f32
    const float* b1    = (const float*)d_in[5];  // (256,) f32
    const float* w2    = (const float*)d_in[6];  // (1,256) f32
    // b2 unused (softmax-invariant shift)

    float* out = (float*)d_out;                  // [user_log | nf], f32
    float* nf  = out + (size_t)B_ * NN_ * NEWS_DIM;

    // d_ws ~256 MiB. Byte offsets, 16B aligned:
    char* ws = (char*)d_ws;
    u16*   lf_bf = (u16*)(ws + 0);               // 3200x448 bf16  (2,867,200 B)
    u16*   Wbf   = (u16*)(ws + 2867200);         // 256x896 bf16   (458,752 B)
    u16*   nv_bf = (u16*)(ws + 3325952);         // 4096x384 bf16  (3,145,728 B)
    float* pn    = (float*)(ws + 6471680);       // 4096x256 f32   (4,194,304 B)
    float* plT   = (float*)(ws + 10665984);      // 64x256x50 f32  (3,276,800 B)

    prep_k    <<<C_TOT / 256, 256, 0, stream>>>(W1, newsv, logv, pos,
                                                Wbf, nv_bf, lf_bf, nf);
    gemm_k    <<<456, 64, 0, stream>>>(nv_bf, lf_bf, Wbf, b1, pn, plT);
    attn_out_k<<<1024, 256, 0, stream>>>(pn, plT, w2, lmask, lf_bf, out);
}